// Round 1
// baseline (1166.909 us; speedup 1.0000x reference)
//
#include <hip/hip_runtime.h>
#include <hip/hip_bf16.h>

#define EMBED_DIM 512
#define SEQ_LEN 8192
#define BATCH 4
#define NUM_BUCKETS 500000u
#define HASH_MASK 8388607u   // 2^23 - 1

// 260^j mod 2^23, computed at compile time
constexpr unsigned powmod(int j) {
    unsigned r = 1u;
    for (int i = 0; i < j; ++i) r = (r * 260u) & HASH_MASK;
    return r;
}

__global__ __launch_bounds__(128) void hash_ngram_kernel(
    const int* __restrict__ tokens,     // [B, S]
    const float* __restrict__ main_w,   // [259, 512]
    const float* __restrict__ shared_w, // [500000, 512]
    const float* __restrict__ size_w,   // [6, 512]
    float* __restrict__ out)            // [B, S, 512]
{
    const int p = blockIdx.x;              // position index in [0, B*S)
    const int s = p & (SEQ_LEN - 1);
    const int b = p >> 13;                 // SEQ_LEN = 8192 = 2^13
    const int d = threadIdx.x << 2;        // float4 offset within the 512-dim row

    const int* trow = tokens + (b << 13);

    // t[j] = tokens[b, s-j] (only needed when s >= n-1, guard OOB with 0)
    unsigned t[8];
#pragma unroll
    for (int j = 0; j < 8; ++j)
        t[j] = (s - j >= 0) ? (unsigned)trow[s - j] : 0u;

    const unsigned P[8] = {powmod(0), powmod(1), powmod(2), powmod(3),
                           powmod(4), powmod(5), powmod(6), powmod(7)};

    // Incremental hash: sum of per-term-masked products; h_n = sum_n & MASK
    unsigned idx[6];
    unsigned sum = 0u;
#pragma unroll
    for (int j = 0; j < 8; ++j) {
        sum += (t[j] * P[j]) & HASH_MASK;
        const int n = j + 1;
        if (n >= 3)
            idx[n - 3] = (s >= n - 1) ? ((sum & HASH_MASK) % NUM_BUCKETS) : 0u;
    }

    // main embedding (table is small and cached)
    float4 acc = *(const float4*)(main_w + (size_t)t[0] * EMBED_DIM + d);

#pragma unroll
    for (int i = 0; i < 6; ++i) {
        const float4 v = *(const float4*)(shared_w + (size_t)idx[i] * EMBED_DIM + d);
        const float4 sz = *(const float4*)(size_w + i * EMBED_DIM + d);
        acc.x += v.x + sz.x;
        acc.y += v.y + sz.y;
        acc.z += v.z + sz.z;
        acc.w += v.w + sz.w;
    }

    const float inv = 1.0f / 7.0f;
    acc.x *= inv; acc.y *= inv; acc.z *= inv; acc.w *= inv;
    *(float4*)(out + (size_t)p * EMBED_DIM + d) = acc;
}

extern "C" void kernel_launch(void* const* d_in, const int* in_sizes, int n_in,
                              void* d_out, int out_size, void* d_ws, size_t ws_size,
                              hipStream_t stream) {
    const int*   tokens   = (const int*)d_in[0];
    const float* main_w   = (const float*)d_in[1];
    const float* shared_w = (const float*)d_in[2];
    const float* size_w   = (const float*)d_in[3];
    float* out = (float*)d_out;

    const int n_pos = BATCH * SEQ_LEN;  // 32768 blocks
    hash_ngram_kernel<<<n_pos, 128, 0, stream>>>(tokens, main_w, shared_w, size_w, out);
}